// Round 14
// baseline (333.495 us; speedup 1.0000x reference)
//
#include <hip/hip_runtime.h>

// Longformer block, MI355X. B=2 S=2048 E=768 H=12 DH=64 W=256 G=16 FF=3072.
// Final configuration (R21 == R17's measured-best 326.3us):
//  - prep: canon + 9 transposes + flags/rope + zero in ONE launch (R13)
//  - projqg: single-buf 128x128 gemm128_core + qg tail (best: 50us; dbuf
//    falsified at 128x128 [+11us, R18] and 128x64 [+4.5us, R20])
//  - band: QBLK=64 async-K dbuf, 1 barrier/unit, XCD swizzle (R8)
//  - gattn: key-split partials, PV loop interchanged (R16)
//  - ffn13: fused silu-gate, 128x64 dual-acc + counted-vmcnt dbuf (R17 WIN)
//  - ffn2: single-buf 128x64 split-K=2 (R16)
//  - addln: residual+LN, global-attn finalize folded in
// T4 ledger: counted-vmcnt dbuf wins ONLY on ffn13's config (32 MFMA/step,
// dual-B, K=768); all transfers falsified. Session best 326.3us; same-code
// cross-container noise band 326-336us.

#define BB_ 2
#define SS 2048
#define EE 768
#define HH 12
#define DHH 64
#define GG 16
#define FFN 3072
#define MM (BB_*SS)   // 4096

typedef __bf16 bf16_t;
typedef __bf16 bf16x8_t __attribute__((ext_vector_type(8)));
typedef float f32x4_t __attribute__((ext_vector_type(4)));

// async global->LDS, 16B per lane; lds dest = wave-uniform base + lane*16
__device__ inline void gload16(const void* g, void* l) {
  __builtin_amdgcn_global_load_lds((const __attribute__((address_space(1))) void*)g,
                                   (__attribute__((address_space(3))) void*)l, 16, 0, 0);
}

// ---------------------------------------------------------------------------
// dtype detector (fp32 vs bf16 inputs).
// ---------------------------------------------------------------------------
__global__ __launch_bounds__(64) void detect_kernel(const unsigned int* __restrict__ w,
                                                    int* __restrict__ flag) {
  int cnt = 0;
  for (int i = threadIdx.x; i < 1024; i += 64) {
    unsigned e = (w[i] >> 7) & 0xFF;
    cnt += (e >= 100 && e <= 144) ? 1 : 0;
  }
  for (int off = 32; off; off >>= 1) cnt += __shfl_xor(cnt, off);
  if (threadIdx.x == 0) flag[0] = (cnt > 512) ? 1 : 0;   // 1 = inputs are bf16
}

// ---------------------------------------------------------------------------
// PREP: canon(x+biases+ln) | transpose x9 | flags+rope | zero accum.
// ---------------------------------------------------------------------------
struct PrepParams {
  const void* csrc[11]; bf16_t* cdst[11];
  const void* tsrc[9];  bf16_t* tdst[9];
  const int* am; const int* gm;
  float* tpos; int* flags;
  float* zbuf; int zn;
};

#define NB_CANON 3081
#define NB_T1 3456    // 6 jobs of 24x24  (EE x EE)
#define NB_T2 4608    // 2 jobs of 96x24  (EE x FFN)
#define NB_T3 2304    // 1 job  of 24x96  (FFN x EE)
#define NB_TRANS (NB_T1+NB_T2+NB_T3)

__global__ __launch_bounds__(256) void prep_kernel(PrepParams P,
                                                   const int* __restrict__ flag) {
  __shared__ bf16_t tile[32][33];
  __shared__ int wtot[4];
  int bid = blockIdx.x;
  const int t = threadIdx.x;
  const bool isb = flag[0] != 0;

  if (bid < NB_CANON) {
    constexpr int ns[11] = {3145728, 768,768,768,768,768,768, 768,768,768,768};
    int idx4 = (bid*256 + t)*4;
    int off = 0, seg = -1, loc = 0;
    #pragma unroll
    for (int i=0;i<11;i++) {
      if (seg < 0 && idx4 < off + ns[i]) { seg = i; loc = idx4 - off; }
      off += ns[i];
    }
    if (seg < 0) return;
    const void* s = P.csrc[seg];
    bf16_t* d = P.cdst[seg];
    if (isb) {
      *(uint2*)&d[loc] = *(const uint2*)((const unsigned short*)s + loc);
    } else {
      float4 v = *(const float4*)((const float*)s + loc);
      d[loc+0] = (bf16_t)v.x; d[loc+1] = (bf16_t)v.y;
      d[loc+2] = (bf16_t)v.z; d[loc+3] = (bf16_t)v.w;
    }
    return;
  }
  bid -= NB_CANON;

  if (bid < NB_TRANS) {
    int job, bx, by, R, C;
    if (bid < NB_T1)            { job = bid/576;          int r = bid%576;  bx = r%24; by = r/24; R=EE;  C=EE;  }
    else if (bid < NB_T1+NB_T2) { int l = bid-NB_T1; job = 6 + l/2304; int r = l%2304; bx = r%96; by = r/96; R=EE;  C=FFN; }
    else                        { int l = bid-NB_T1-NB_T2; job = 8;          bx = l%24; by = l/24; R=FFN; C=EE;  }
    const void* src = P.tsrc[job]; bf16_t* dst = P.tdst[job];
    int tx = t & 31, ty = t >> 5;
    int r0 = by*32, c0 = bx*32;
    #pragma unroll
    for (int i=0;i<4;i++) {
      int rr = ty + i*8;
      size_t si = (size_t)(r0+rr)*C + c0 + tx;
      tile[rr][tx] = isb ? ((const bf16_t*)src)[si] : (bf16_t)((const float*)src)[si];
    }
    __syncthreads();
    #pragma unroll
    for (int i=0;i<4;i++) {
      int cc = ty + i*8;
      dst[(size_t)(c0+cc)*R + r0 + tx] = tile[tx][cc];
    }
    return;
  }
  bid -= NB_TRANS;

  if (bid < BB_) {
    int b = bid;
    int lane = t & 63, wv = t >> 6;
    int base = b*SS + t*8;
    int mg[8]; int isg[8]; int loc = 0;
    for (int i=0;i<8;i++) {
      int a = P.am[base+i], g = P.gm[base+i];
      int merged = a*(g+1);
      mg[i] = merged;
      isg[i] = (merged==2) ? 1 : 0;
      loc += isg[i];
    }
    int x = loc;
    for (int off=1; off<64; off<<=1) {
      int y = __shfl_up(x, off);
      if (lane >= off) x += y;
    }
    if (lane==63) wtot[wv] = x;
    __syncthreads();
    int prev = 0;
    for (int w=0; w<wv; w++) prev += wtot[w];
    int run = prev + x - loc;
    for (int i=0;i<8;i++) {
      run += isg[i];
      int masked = (mg[i]==0) ? 1 : 0;
      int glob   = (mg[i]==2) ? 1 : 0;
      int rem    = (mg[i]!=1) ? 1 : 0;
      P.tpos[base+i]  = masked ? 0.f : (float)run;
      P.flags[base+i] = masked | (glob<<1) | (rem<<2);
    }
    return;
  }
  bid -= BB_;
  int i = bid*256 + t;
  if (i < P.zn) P.zbuf[i] = 0.f;
}

// ---------------------------------------------------------------------------
// 128x128-tile BK=64 GEMM core with XOR chunk swizzle (single-buffered).
// ---------------------------------------------------------------------------
__device__ inline void gemm128_core(const bf16_t* __restrict__ A,
                                    const bf16_t* __restrict__ BT,
                                    int ldA, int ldB, int kbeg, int kend,
                                    int m0, int n0,
                                    bf16_t* As, bf16_t* Bs,
                                    f32x4_t (&acc)[4][4]) {
  const int t = threadIdx.x;
  const int lane = t & 63, wv = t >> 6;
  const int l15 = lane & 15, quad = lane >> 4;
  const int wr = (wv >> 1) << 6, wc = (wv & 1) << 6;
  const int rsub = lane >> 3, pch = lane & 7;    // staging row-sub / chunk pos
  const int sch = pch ^ rsub;                    // swizzled source chunk
  const size_t abase = (size_t)(m0 + wv*32 + rsub)*ldA + sch*8;
  const size_t bbase = (size_t)(n0 + wv*32 + rsub)*ldB + sch*8;
  const int sx = l15 & 7;                        // read-side swizzle
  bf16_t* lA = As + (wv*32)*64;
  bf16_t* lB = Bs + (wv*32)*64;
  for (int k0 = kbeg; k0 < kend; k0 += 64) {
    __syncthreads();
    #pragma unroll
    for (int j=0;j<4;j++) {
      gload16(A + abase + (size_t)(j*8)*ldA + k0, lA + j*8*64);
      gload16(BT + bbase + (size_t)(j*8)*ldB + k0, lB + j*8*64);
    }
    __syncthreads();
    #pragma unroll
    for (int c=0;c<2;c++) {
      bf16x8_t af[4], bfr[4];
      #pragma unroll
      for (int a=0;a<4;a++)
        af[a] = *(const bf16x8_t*)&As[(wr + a*16 + l15)*64 + ((c*4+quad)^sx)*8];
      #pragma unroll
      for (int b=0;b<4;b++)
        bfr[b] = *(const bf16x8_t*)&Bs[(wc + b*16 + l15)*64 + ((c*4+quad)^sx)*8];
      #pragma unroll
      for (int a=0;a<4;a++)
        #pragma unroll
        for (int b=0;b<4;b++)
          acc[a][b] = __builtin_amdgcn_mfma_f32_16x16x32_bf16(af[a], bfr[b], acc[a][b], 0,0,0);
    }
  }
}

// ---------------------------------------------------------------------------
// Fused QKV(+global KV) projection + qg tail blocks.
// blocks [0,960): proj z: 0=q(scale+rope) 1=k(rope) 2=v 3=kg 4=vg
// blocks [960,1056): qg repacked 4 heads/block (256 thr = 4 waves).
// ---------------------------------------------------------------------------
struct ProjParams {
  const bf16_t* W[5];   // transposed [N][K]
  const bf16_t* Bi[5];
  bf16_t* O[5];
};

__global__ __launch_bounds__(256) void projqg_kernel(const bf16_t* __restrict__ x,
                                                     ProjParams P,
                                                     const float* __restrict__ tpos,
                                                     const bf16_t* __restrict__ WqgT,
                                                     const bf16_t* __restrict__ bqg,
                                                     float* __restrict__ qgb) {
  __shared__ bf16_t As[128*64];
  __shared__ bf16_t Bs[128*64];
  const int bid = blockIdx.x;
  const int t = threadIdx.x;
  const int lane = t & 63, wv = t >> 6;

  if (bid >= 960) {
    // ---- qg: block covers (g, hgroup, b); wave wv -> head hgroup*4+wv
    int l = bid - 960;               // [0,96)
    int g = l & 15;
    int rest = l >> 4;               // [0,6)
    int hg = rest % 3, b = rest / 3;
    float* xs = (float*)As;          // 768 floats = 3 KB
    for (int i=t; i<EE; i+=256) xs[i] = (float)x[((size_t)b*SS + g)*EE + i];
    __syncthreads();
    int h = hg*4 + wv, d = lane;
    float acc = 0.f;
    const bf16_t* wrow = WqgT + (size_t)(h*64+d)*EE;
    #pragma unroll 4
    for (int k=0;k<EE;k+=8) {
      bf16x8_t w8 = *(const bf16x8_t*)(wrow + k);
      #pragma unroll
      for (int i=0;i<8;i++) acc += xs[k+i] * (float)w8[i];
    }
    acc = (acc + (float)bqg[h*64+d]) * 0.125f;
    qgb[((size_t)(b*HH+h)*GG + g)*DHH + d] = acc;
    return;
  }

  const int z  = bid / 192;
  const int rem = bid % 192;
  const int m0 = (rem % 32)*128, n0 = (rem / 32)*128;
  f32x4_t acc[4][4];
  #pragma unroll
  for (int a=0;a<4;a++)
    #pragma unroll
    for (int b=0;b<4;b++) acc[a][b] = (f32x4_t){0.f,0.f,0.f,0.f};
  gemm128_core(x, P.W[z], EE, EE, 0, EE, m0, n0, As, Bs, acc);

  const int l15 = lane & 15, quad = lane >> 4;
  const int wr = (wv >> 1) << 6, wc = (wv & 1) << 6;
  const float scale = (z==0) ? 0.125f : 1.f;
  const bool rope = (z<2);
  const int h = (n0 + wc) >> 6;          // one head per wave half-tile
  bf16_t* Oz = P.O[z];
  const bf16_t* Bz = P.Bi[z];
  float bvals[4];
  #pragma unroll
  for (int b=0;b<4;b++) bvals[b] = (float)Bz[h*64 + b*16 + l15];
  #pragma unroll
  for (int a=0;a<4;a++) {
    #pragma unroll
    for (int r=0;r<4;r++) {
      int row = m0 + wr + a*16 + quad*4 + r;
      int bb = row >> 11, spos = row & (SS-1);
      float vals[4];
      #pragma unroll
      for (int b=0;b<4;b++) vals[b] = (acc[a][b][r] + bvals[b]) * scale;
      if (rope) {
        float tv = tpos[row];
        #pragma unroll
        for (int b=0;b<2;b++) {
          int j = b*16 + l15;                   // freq index in [0,32)
          float inv = __expf(-(float)j * (9.210340371976184f/32.f));
          float ang = tv * inv;
          float sn = __sinf(ang), cs = __cosf(ang);
          float x1 = vals[b], x2 = vals[b+2];
          vals[b]   = x1*cs - x2*sn;
          vals[b+2] = x2*cs + x1*sn;
        }
      }
      bf16_t* dst = Oz + ((size_t)(bb*HH + h)*SS + spos)*DHH;
      #pragma unroll
      for (int b=0;b<4;b++) dst[b*16 + l15] = (bf16_t)vals[b];
    }
  }
}

// ---------------------------------------------------------------------------
// Fused FFN1+FFN3: g1 = silu(h0@W1) * (h0@W3). 128x64 tile, dual accumulators.
// R17 counted-vmcnt double-buffer (verified win; the one T4 success).
// ---------------------------------------------------------------------------
__global__ __launch_bounds__(256) void gemm_ffn13(const bf16_t* __restrict__ A,
                                                  const bf16_t* __restrict__ B1T,
                                                  const bf16_t* __restrict__ B3T,
                                                  bf16_t* __restrict__ g1) {
  const int n0 = blockIdx.x*64, m0 = blockIdx.y*128;
  __shared__ bf16_t As[2][128*64];
  __shared__ bf16_t Bs1[2][64*64];
  __shared__ bf16_t Bs3[2][64*64];
  const int t = threadIdx.x;
  const int lane = t & 63, wv = t >> 6;
  const int l15 = lane & 15, quad = lane >> 4;
  const int wr = (wv >> 1) << 6, wc = (wv & 1) << 5;   // 64 rows x 32 cols / wave
  const int rsub = lane >> 3, pch = lane & 7;
  const int sch = pch ^ rsub;                          // swizzled source chunk
  const size_t abase = (size_t)(m0 + wv*32 + rsub)*EE + sch*8;
  const size_t bbase = (size_t)(n0 + wv*16 + rsub)*EE + sch*8;
  const int sx = l15 & 7;
  const int aoff = (wv*32)*64, boff = (wv*16)*64;

  f32x4_t a1[4][2], a3[4][2];
  #pragma unroll
  for (int a=0;a<4;a++)
    #pragma unroll
    for (int b=0;b<2;b++) { a1[a][b] = (f32x4_t){0.f,0.f,0.f,0.f};
                            a3[a][b] = (f32x4_t){0.f,0.f,0.f,0.f}; }

  #define FFN13_STAGE(buf, k0) do { \
    bf16_t* lA  = &As[buf][aoff]; \
    bf16_t* lB1 = &Bs1[buf][boff]; \
    bf16_t* lB3 = &Bs3[buf][boff]; \
    _Pragma("unroll") \
    for (int j=0;j<4;j++) \
      gload16(A + abase + (size_t)(j*8)*EE + (k0), lA + j*8*64); \
    _Pragma("unroll") \
    for (int j=0;j<2;j++) { \
      gload16(B1T + bbase + (size_t)(j*8)*EE + (k0), lB1 + j*8*64); \
      gload16(B3T + bbase + (size_t)(j*8)*EE + (k0), lB3 + j*8*64); \
    } } while(0)

  FFN13_STAGE(0, 0);
  FFN13_STAGE(1, 64);
  asm volatile("s_waitcnt vmcnt(8)" ::: "memory");
  __builtin_amdgcn_sched_barrier(0);
  __builtin_amdgcn_s_barrier();

  for (int s = 0; s < 12; ++s) {
    const int cur = s & 1;
    const bf16_t* Ac = As[cur];
    const bf16_t* C1 = Bs1[cur];
    const bf16_t* C3 = Bs3[cur];
    bf16x8_t af[2][4], b1f[2][2], b3f[2][2];
    #pragma unroll
    for (int c=0;c<2;c++) {
      #pragma unroll
      for (int a=0;a<4;a++)
        af[c][a] = *(const bf16x8_t*)&Ac[(wr + a*16 + l15)*64 + ((c*4+quad)^sx)*8];
      #pragma unroll
      for (int b=0;b<2;b++) {
        b1f[c][b] = *(const bf16x8_t*)&C1[(wc + b*16 + l15)*64 + ((c*4+quad)^sx)*8];
        b3f[c][b] = *(const bf16x8_t*)&C3[(wc + b*16 + l15)*64 + ((c*4+quad)^sx)*8];
      }
    }
    asm volatile("s_waitcnt lgkmcnt(0)" ::: "memory");
    __builtin_amdgcn_sched_barrier(0);
    __builtin_amdgcn_s_barrier();            // all waves done reading buf[cur]
    if (s + 2 < 12) FFN13_STAGE(cur, (s+2)*64);
    __builtin_amdgcn_s_setprio(1);
    #pragma unroll
    for (int c=0;c<2;c++)
      #pragma unroll
      for (int a=0;a<4;a++)
        #pragma unroll
        for (int b=0;b<2;b++) {
          a1[a][b] = __builtin_amdgcn_mfma_f32_16x16x32_bf16(af[c][a], b1f[c][b], a1[a][b], 0,0,0);
          a3[a][b] = __builtin_amdgcn_mfma_f32_16x16x32_bf16(af[c][a], b3f[c][b], a3[a][b], 0,0,0);
        }
    __builtin_amdgcn_s_setprio(0);
    if (s + 1 < 12) {
      if (s + 2 < 12) {
        asm volatile("s_waitcnt vmcnt(8)" ::: "memory");
      } else {
        asm volatile("s_waitcnt vmcnt(0)" ::: "memory");
      }
      __builtin_amdgcn_sched_barrier(0);
      __builtin_amdgcn_s_barrier();
    }
  }
  #undef FFN13_STAGE

  #pragma unroll
  for (int a=0;a<4;a++)
    #pragma unroll
    for (int r=0;r<4;r++) {
      int row = m0 + wr + a*16 + quad*4 + r;
      #pragma unroll
      for (int b=0;b<2;b++) {
        float tv = a1[a][b][r];
        float sil = tv / (1.f + __expf(-tv));
        g1[(size_t)row*FFN + n0 + wc + b*16 + l15] = (bf16_t)(sil * a3[a][b][r]);
      }
    }
}

// ---------------------------------------------------------------------------
// FFN down, 128x64 tile (single-buf), split-K=2 (R16 form).
// ---------------------------------------------------------------------------
struct Ffn2Out { float* p[2]; };

__global__ __launch_bounds__(256) void gemm_ffn2(const bf16_t* __restrict__ A,
                                                 const bf16_t* __restrict__ BT,
                                                 Ffn2Out O) {
  const int n0 = blockIdx.x*64, m0 = blockIdx.y*128;
  const int kz = blockIdx.z;
  __shared__ bf16_t As[128*64];
  __shared__ bf16_t Bs[64*64];
  const int t = threadIdx.x;
  const int lane = t & 63, wv = t >> 6;
  const int l15 = lane & 15, quad = lane >> 4;
  const int wr = (wv >> 1) << 6, wc = (wv & 1) << 5;   // 64 rows x 32 cols / wave
  const int rsub = lane >> 3, pch = lane & 7;
  const int sch = pch ^ rsub;
  const size_t abase = (size_t)(m0 + wv*32 + rsub)*FFN + sch*8;
  const size_t bbase = (size_t)(n0 + wv*16 + rsub)*FFN + sch*8;
  const int sx = l15 & 7;
  bf16_t* lA = As + (wv*32)*64;
  bf16_t* lB = Bs + (wv*16)*64;
  f32x4_t acc[4][2];
  #pragma unroll
  for (int a=0;a<4;a++)
    #pragma unroll
    for (int b=0;b<2;b++) acc[a][b] = (f32x4_t){0.f,0.f,0.f,0.f};
  const int kbeg = kz*1536, kend = kbeg + 1536;
  for (int k0 = kbeg; k0 < kend; k0 += 64) {
    __syncthreads();
    #pragma unroll
    for (int j=0;j<4;j++)
      gload16(A + abase + (size_t)(j*8)*FFN + k0, lA + j*8*64);
    #pragma unroll
    for (int j=0;j<2;j++)
      gload16(BT + bbase + (size_t)(j*8)*FFN + k0, lB + j*8*64);
    __syncthreads();
    #pragma unroll
    for (int c=0;c<2;c++) {
      bf16x8_t af[4], bfv[2];
      #pragma unroll
      for (int a=0;a<4;a++)
        af[a] = *(const bf16x8_t*)&As[(wr + a*16 + l15)*64 + ((c*4+quad)^sx)*8];
      #pragma unroll
      for (int b=0;b<2;b++)
        bfv[b] = *(const bf16x8_t*)&Bs[(wc + b*16 + l15)*64 + ((c*4+quad)^sx)*8];
      #pragma unroll
      for (int a=0;a<4;a++)
        #pragma unroll
        for (int b=0;b<2;b++)
          acc[a][b] = __builtin_amdgcn_mfma_f32_16x16x32_bf16(af[a], bfv[b], acc[a][b], 0,0,0);
    }
  }
  float* C = O.p[kz];
  #pragma unroll
  for (int a=0;a<4;a++)
    #pragma unroll
    for (int r=0;r<4;r++) {
      int row = m0 + wr + a*16 + quad*4 + r;
      #pragma unroll
      for (int b=0;b<2;b++)
        C[(size_t)row*EE + n0 + wc + b*16 + l15] = acc[a][b][r];
    }
}

// ---------------------------------------------------------------------------
// Band (sliding-window) attention, MFMA. QBLK=64, standalone (48 VGPR shape).
// ---------------------------------------------------------------------------
__global__ __launch_bounds__(256) void band_kernel(const bf16_t* __restrict__ qb,
                                                   const bf16_t* __restrict__ kb,
                                                   const bf16_t* __restrict__ vb,
                                                   const int* __restrict__ flags,
                                                   float* __restrict__ attn) {
  const int flat = blockIdx.x;
  const int nb = (flat & 7) * 96 + (flat >> 3);
  const int px = nb & 31;
  const int hb = nb >> 5;              // 0..23
  const int h = hb % HH, b = hb / HH;
  const int p0 = px * 64;

  const int t = threadIdx.x;
  const int wv = t>>6, lane = t&63;
  const int l15 = lane & 15, quad = lane >> 4;
  const size_t bh = (size_t)(b*HH+h);
  const bf16_t* kbh = kb + bh*SS*DHH;
  const bf16_t* vbh = vb + bh*SS*DHH;
  const int* fl = flags + b*SS;
  const int q0 = p0 + wv*16;

  __shared__ bf16_t Ks[2][64*DHH];      // [buf][key][dh], XOR chunk-swizzled
  __shared__ bf16_t Vt[2][64*72];       // [buf][dh][key]
  __shared__ bf16_t Pw[4][16*72];       // per-wave P [q][key]

  const bf16_t* qrow = qb + (bh*SS + q0 + l15)*DHH;
  bf16x8_t qa0 = *(const bf16x8_t*)(qrow + quad*8);
  bf16x8_t qa1 = *(const bf16x8_t*)(qrow + 32 + quad*8);

  const int srsub = lane >> 3, spch = lane & 7;
  const int vkp  = (t & 31) * 2;
  const int vdh0 = (t >> 5) * 8;

  // ---- prologue: stage unit 0 into buf 0
  {
    const int kb0 = p0 - 256;
    #pragma unroll
    for (int j=0;j<2;j++) {
      int row = wv*16 + j*8 + srsub;
      int kc = min(max(kb0 + row, 0), SS-1);
      gload16(kbh + (size_t)kc*DHH + (spch ^ srsub)*8, &Ks[0][(wv*16 + j*8)*DHH]);
    }
    int kc1 = min(max(kb0 + vkp,   0), SS-1);
    int kc2 = min(max(kb0 + vkp+1, 0), SS-1);
    bf16x8_t v1 = *(const bf16x8_t*)(vbh + (size_t)kc1*DHH + vdh0);
    bf16x8_t v2 = *(const bf16x8_t*)(vbh + (size_t)kc2*DHH + vdh0);
    #pragma unroll
    for (int i=0;i<8;i++) {
      union { unsigned u; bf16_t hh[2]; } pk;
      pk.hh[0] = v1[i]; pk.hh[1] = v2[i];
      *(unsigned*)&Vt[0][(vdh0+i)*72 + vkp] = pk.u;
    }
  }
  __syncthreads();

  f32x4_t o[4];
  #pragma unroll
  for (int i=0;i<4;i++) o[i] = (f32x4_t){0.f,0.f,0.f,0.f};
  float lsum[4] = {0.f,0.f,0.f,0.f};
  bf16_t* P = Pw[wv];

  for (int unit=0; unit<10; unit++) {
    const int cur = unit & 1, nxt = cur ^ 1;
    const int kb0 = (unit<9) ? (p0 - 256 + unit*64) : 0;
    const bool pre = (unit < 9);
    bf16x8_t pv1, pv2;
    if (pre) {
      const int kbn = (unit < 8) ? (kb0 + 64) : 0;
      #pragma unroll
      for (int j=0;j<2;j++) {
        int row = wv*16 + j*8 + srsub;
        int kc = min(max(kbn + row, 0), SS-1);
        gload16(kbh + (size_t)kc*DHH + (spch ^ srsub)*8, &Ks[nxt][(wv*16 + j*8)*DHH]);
      }
      int kc1 = min(max(kbn + vkp,   0), SS-1);
      int kc2 = min(max(kbn + vkp+1, 0), SS-1);
      pv1 = *(const bf16x8_t*)(vbh + (size_t)kc1*DHH + vdh0);
      pv2 = *(const bf16x8_t*)(vbh + (size_t)kc2*DHH + vdh0);
    }
    // ---- QK^T + exp from Ks[cur]
    const bf16_t* Kc = Ks[cur];
    const int nsub = (unit<9) ? 4 : 1;
    for (int sub=0; sub<4; sub++) {
      if (sub < nsub) {
        int krow = sub*16 + l15;
        int kpos = kb0 + krow;
        bf16x8_t kf0 = *(const bf16x8_t*)&Kc[krow*DHH + (((quad  ) ^ (krow&7))<<3)];
        bf16x8_t kf1 = *(const bf16x8_t*)&Kc[krow*DHH + (((quad+4) ^ (krow&7))<<3)];
        f32x4_t s = (f32x4_t){0.f,0.f,0.f,0.f};
        s = __builtin_amdgcn_mfma_f32_16x16x32_bf16(qa0, kf0, s, 0,0,0);
        s = __builtin_amdgcn_mfma_f32_16x16x32_bf16(qa1, kf1, s, 0,0,0);
        int kc = min(max(kpos,0),SS-1);
        bool drop = false;
        if (unit<9) drop = (kpos<0) || (kpos>=SS) || (((fl[kc]>>2)&1)!=0);
        #pragma unroll
        for (int r=0;r<4;r++) {
          float e;
          if (unit==9) {
            e = __expf(s[r]);
          } else {
            int dj = kpos - (q0 + quad*4 + r);
            bool valid = (dj>=-256) && (dj<=256) && (!drop);
            e = valid ? __expf(s[r]) : 0.f;
          }
          lsum[r] += e;
          P[(quad*4+r)*72 + sub*16 + l15] = (bf16_t)e;
        }
      } else {
        #pragma unroll
        for (int r=0;r<4;r++) P[(quad*4+r)*72 + sub*16 + l15] = (bf16_t)0.f;
      }
    }
    // ---- P @ V from Vt[cur]
    __builtin_amdgcn_s_setprio(1);
    #pragma unroll
    for (int chunk=0; chunk<2; chunk++) {
      bf16x8_t pf = *(const bf16x8_t*)&P[l15*72 + chunk*32 + quad*8];
      #pragma unroll
      for (int nt=0; nt<4; nt++) {
        bf16x8_t vf = *(const bf16x8_t*)&Vt[cur][(nt*16+l15)*72 + chunk*32 + quad*8];
        o[nt] = __builtin_amdgcn_mfma_f32_16x16x32_bf16(pf, vf, o[nt], 0,0,0);
      }
    }
    __builtin_amdgcn_s_setprio(0);
    // ---- late transpose-write of prefetched V into the free buffer
    if (pre) {
      #pragma unroll
      for (int i=0;i<8;i++) {
        union { unsigned u; bf16_t hh[2]; } pk;
        pk.hh[0] = pv1[i]; pk.hh[1] = pv2[i];
        *(unsigned*)&Vt[nxt][(vdh0+i)*72 + vkp] = pk.u;
      }
      __syncthreads();   // one barrier per unit; implicit vmcnt(0) drains gload_lds
    }
  }
  #pragma unroll
  for (int r=0;r<4;r++) {
    float s = lsum[r];
    s += __shfl_xor(s,1); s += __shfl_xor(s,2);
    s += __shfl_xor(s,4); s += __shfl_xor(s,8);
    lsum[r] = s;
  }
  #pragma unroll
  for (int r=0;r<4;r++) {
    int q = q0 + quad*4 + r;
    int masked = fl[q] & 1;
    float inv = masked ? 0.f : 1.f/lsum[r];
    float* dst = attn + ((size_t)(b*SS+q))*EE + h*64 + l15;
    #pragma unroll
    for (int nt=0; nt<4; nt++) dst[nt*16] = o[nt][r]*inv;
  }
}

// ---------------------------------------------------------------------------
// Global attention, key-split partials (finalize folded into addln).
// ---------------------------------------------------------------------------
__global__ __launch_bounds__(256) void gattn_part(const float* __restrict__ qgb,
                                                  const bf16_t* __restrict__ kgb,
                                                  const bf16_t* __restrict__ vgb,
                                                  const int* __restrict__ flags,
                                                  float* __restrict__ go,
                                                  float* __restrict__ gl) {
  const int kbase = blockIdx.x*128;
  const int h = blockIdx.y, b = blockIdx.z;
  const int t = threadIdx.x;
  __shared__ float gqs[16*68];
  __shared__ float Ks[64*68];
  __shared__ float Vs[64*68];
  __shared__ float es[16*64];
  const size_t bh = (size_t)(b*HH+h);
  #pragma unroll
  for (int j=0;j<4;j++) {
    int idx = t + j*256;
    int g = idx>>6, d = idx&63;
    gqs[g*68+d] = qgb[(bh*GG + g)*DHH + d];
  }
  float accv[4] = {0.f,0.f,0.f,0.f};
  float lpart = 0.f;
  const int gs = t>>4, kslot = t&15;
  const int dp = t&63, grp = t>>6;
  const bf16_t* kb_ = kgb + bh*SS*DHH;
  const bf16_t* vb_ = vgb + bh*SS*DHH;
  const int* fl = flags + b*SS;
  for (int tile=0; tile<2; tile++) {
    int k0 = kbase + tile*64;
    __syncthreads();
    {
      int row = t>>2, seg = t&3;
      const bf16_t* sk = kb_ + (size_t)(k0+row)*DHH + seg*16;
      const bf16_t* sv = vb_ + (size_t)(k0+row)*DHH + seg*16;
      bf16x8_t k1 = *(const bf16x8_t*)sk;
      bf16x8_t k2 = *(const bf16x8_t*)(sk+8);
      bf16x8_t v1 = *(const bf16x8_t*)sv;
      bf16x8_t v2 = *(const bf16x8_t*)(sv+8);
      #pragma unroll
      for (int i=0;i<8;i++) {
        Ks[row*68 + seg*16 + i]     = (float)k1[i];
        Ks[row*68 + seg*16 + 8 + i] = (float)k2[i];
        Vs[row*68 + seg*16 + i]     = (float)v1[i];
        Vs[row*68 + seg*16 + 8 + i] = (float)v2[i];
      }
    }
    __syncthreads();
    #pragma unroll
    for (int j=0;j<4;j++) {
      int key = kslot + 16*j;
      const float* gq = &gqs[gs*68];
      const float* kr = &Ks[key*68];
      float s = 0.f;
      #pragma unroll
      for (int d4=0; d4<64; d4+=4) {
        float4 a = *(const float4*)(gq + d4);
        float4 kk = *(const float4*)(kr + d4);
        s += a.x*kk.x + a.y*kk.y + a.z*kk.z + a.w*kk.w;
      }
      int msk = fl[k0+key] & 1;
      float e = msk ? 0.f : __expf(s);
      es[gs*64+key] = e;
      lpart += e;
    }
    __syncthreads();
    #pragma unroll 8
    for (int key=0; key<64; key++) {
      float vv = Vs[key*68+dp];
      #pragma unroll
      for (int g=0; g<4; g++)
        accv[g] += es[(grp*4+g)*64+key]*vv;
    }
  }
  __syncthreads();
  es[gs*64 + kslot] = lpart;
  __syncthreads();
  if (t < 16) {
    float s = 0.f;
    for (int j=0;j<16;j++) s += es[t*64+j];
    atomicAdd(&gl[bh*16 + t], s);
  }
  #pragma unroll
  for (int g=0; g<4; g++)
    atomicAdd(&go[(bh*16 + grp*4+g)*64 + dp], accv[g]);
}

// ---------------------------------------------------------------------------
// Residual add + LayerNorm. B-side = sum of up to 4 fp32 partials (each
// individually optional). If gof!=nullptr, rows with (r mod S) < G take the
// attention value from go/gl (global-attention overwrite) instead of B0.
// ---------------------------------------------------------------------------
__global__ __launch_bounds__(256) void addln_kernel(const bf16_t* __restrict__ Abf,
                                                    const float* __restrict__ Af,
                                                    const float* __restrict__ B0,
                                                    const float* __restrict__ B1,
                                                    const float* __restrict__ B2,
                                                    const float* __restrict__ B3,
                                                    const float* __restrict__ gof,
                                                    const float* __restrict__ glf,
                                                    const bf16_t* __restrict__ gw,
                                                    const bf16_t* __restrict__ bw,
                                                    float* __restrict__ outf,
                                                    bf16_t* __restrict__ outb,
                                                    const int* __restrict__ flagp) {
  int r = blockIdx.x, t = threadIdx.x;
  int lane = t&63, wv = t>>6;
  int spos = r & (SS-1), bb = r >> 11;
  bool isglob = (gof != nullptr) && (spos < GG);
  float v[3]; float sum=0.f, ss=0.f;
  #pragma unroll
  for (int j=0;j<3;j++) {
    int idx = t + j*256;
    size_t gi = (size_t)r*EE+idx;
    float a = Abf ? (float)Abf[gi] : Af[gi];
    float bv;
    if (isglob) {
      int hh = idx >> 6, dp = idx & 63;
      int slot = (bb*HH + hh)*GG + spos;
      bv = gof[(size_t)slot*DHH + dp] / glf[slot];
    } else {
      bv = B0[gi];
    }
    float val = a + bv;
    if (B1) val += B1[gi];
    if (B2) val += B2[gi];
    if (B3) val += B3[gi];
    v[j] = val; sum += val; ss += val*val;
  }
  #pragma unroll
  for (int off=32; off>=1; off>>=1) {
    sum += __shfl_xor(sum, off);
    ss  += __shfl_xor(ss, off);
  }
  __shared__ float s1[4], s2[4];
  if (lane==0) { s1[wv]=sum; s2[wv]=ss; }
  __syncthreads();
  sum = s1[0]+s1[1]+s1[2]+s1[3];
  ss  = s2[0]+s2[1]+s2[2]+s2[3];
  float mean = sum * (1.f/(float)EE);
  float var  = ss * (1.f/(float)EE) - mean*mean;
  float rstd = rsqrtf(var + 1e-5f);
  bool wantb, wantf;
  if (flagp) { bool isb = (*flagp)!=0; wantb = isb; wantf = !isb; }
  else { wantb = (outb!=nullptr); wantf = (outf!=nullptr); }
  #pragma unroll
  for (int j=0;j<3;j++) {
    int idx = t + j*256;
    float o = (v[j]-mean)*rstd*(float)gw[idx] + (float)bw[idx];
    if (wantf) outf[(size_t)r*EE+idx] = o;
    if (wantb) outb[(size_t)r*EE+idx] = (bf16_t)o;
  }
}

// ---------------------------------------------------------------------------
extern "C" void kernel_launch(void* const* d_in, const int* in_sizes, int n_in,
                              void* d_out, int out_size, void* d_ws, size_t ws_size,
                              hipStream_t stream) {
  const void* x_r    = d_in[0];
  const int* am      = (const int*)d_in[1];
  const int* gm      = (const int*)d_in[2];
  (void)in_sizes; (void)n_in; (void)out_size; (void)ws_size;

  char* ws = (char*)d_ws;
  size_t off = 0;
  auto alloc = [&](size_t bytes) -> void* {
    void* p = ws + off;
    off += (bytes + 255) & ~(size_t)255;
    return p;
  };
  // canonical bf16 tensors (weights transposed to [N][K])
  bf16_t* xc    = (bf16_t*)alloc((size_t)MM*EE*2);
  bf16_t* WT[6]; bf16_t* bc[6];
  for (int i=0;i<6;i++) { WT[i] = (bf16_t*)alloc((size_t)EE*EE*2); bc[i] = (bf16_t*)alloc(EE*2); }
  bf16_t* lnc[4];
  for (int i=0;i<4;i++) lnc[i] = (bf16_t*)alloc(EE*2);
  bf16_t* W1T = (bf16_t*)alloc((size_t)EE*FFN*2);
  bf16_t* W3T = (bf16_t*)alloc((size_t)EE*FFN*2);
  bf16_t* W2T = (bf16_t*)alloc((size_t)FFN*EE*2);
  // intermediates
  const size_t NBHSD = (size_t)BB_*HH*SS*DHH;
  bf16_t* qb    = (bf16_t*)alloc(NBHSD*2);
  bf16_t* kb    = (bf16_t*)alloc(NBHSD*2);
  bf16_t* vb    = (bf16_t*)alloc(NBHSD*2);
  bf16_t* kgb   = (bf16_t*)alloc(NBHSD*2);
  bf16_t* vgb   = (bf16_t*)alloc(NBHSD*2);
  float* qgb   = (float*)alloc((size_t)BB_*HH*GG*DHH*4);
  float* attn  = (float*)alloc((size_t)MM*EE*4);    // reused as ffn2 partial 0
  float* h0f   = (float*)alloc((size_t)MM*EE*4);
  bf16_t* h0b  = (bf16_t*)alloc((size_t)MM*EE*2);
  bf16_t* g1   = (bf16_t*)alloc((size_t)MM*FFN*2);
  float* go    = (float*)alloc((size_t)BB_*HH*GG*DHH*4);  // 24576 f32
  float* gl    = (float*)alloc((size_t)BB_*HH*GG*4);      // 384 f32 (contiguous)
  float* tposb = (float*)alloc((size_t)BB_*SS*4);
  int*   flagb = (int*)alloc((size_t)BB_*SS*4);
  int*   dflag = (int*)alloc(256);
  // ffn2 partial 1 aliases qb+kb (12.6MB fp32, dead after attention)
  float* p1 = (float*)qb;

  // 0. dtype detect on Wq
  detect_kernel<<<1, 64, 0, stream>>>((const unsigned int*)d_in[3], dflag);

  // 1. prep: canon + 9 transposes + flags/rope + zero accumulators (ONE launch)
  PrepParams PP;
  const void* csrc[11] = { x_r, d_in[4], d_in[6], d_in[8], d_in[10], d_in[12], d_in[14],
                           d_in[15], d_in[16], d_in[17], d_in[18] };
  bf16_t* cdst[11] = { xc, bc[0], bc[1], bc[2], bc[3], bc[4], bc[5],
                       lnc[0], lnc[1], lnc[2], lnc[3] };
  for (int i=0;i<11;i++) { PP.csrc[i]=csrc[i]; PP.cdst[i]=cdst[i]; }
  const int wi[6] = {3,5,7,9,11,13};                 // Wq Wk Wv Wqg Wkg Wvg
  for (int i=0;i<6;i++) { PP.tsrc[i]=d_in[wi[i]]; PP.tdst[i]=WT[i]; }
  PP.tsrc[6]=d_in[19]; PP.tdst[6]=W1T;
  PP.tsrc[7]=d_in[20]; PP.tdst[7]=W3T;
  PP.tsrc[8]=d_in[21]; PP.tdst[8]=W2T;
  PP.am = am; PP.gm = gm; PP.tpos = tposb; PP.flags = flagb;
  PP.zbuf = go; PP.zn = 24960;                       // go+gl contiguous
  prep_kernel<<<NB_CANON + NB_TRANS + BB_ + 98, 256, 0, stream>>>(PP, dflag);

  // 2. fused projections (q,k,v,kg,vg; single-buf 128x128) + qg tail
  ProjParams P;
  P.W[0]=WT[0]; P.Bi[0]=bc[0]; P.O[0]=qb;
  P.W[1]=WT[1]; P.Bi[1]=bc[1]; P.O[1]=kb;
  P.W[2]=WT[2]; P.Bi[2]=bc[2]; P.O[2]=vb;
  P.W[3]=WT[4]; P.Bi[3]=bc[4]; P.O[3]=kgb;   // Wkg
  P.W[4]=WT[5]; P.Bi[4]=bc[5]; P.O[4]=vgb;   // Wvg
  projqg_kernel<<<dim3(1056), 256, 0, stream>>>(xc, P, tposb, WT[3], bc[3], qgb);

  // 3. band attention (standalone, 768 blocks, XCD-swizzled)
  band_kernel<<<dim3(768), 256, 0, stream>>>(qb, kb, vb, flagb, attn);

  // 4. global-attention rows (key-split partials; finalize folded into addln)
  gattn_part<<<dim3(SS/128, HH, BB_), 256, 0, stream>>>(qgb, kgb, vgb, flagb, go, gl);

  // 5. h0 = LN(x + attn)   (rows < G take go/gl)
  addln_kernel<<<MM, 256, 0, stream>>>(xc, nullptr, attn, nullptr, nullptr, nullptr,
                                       go, gl, lnc[0], lnc[1], h0f, h0b, nullptr);

  // 6. FFN: fused ffn13 (dbuf, verified) -> g1, then 128x64 splitK2 down-proj
  gemm_ffn13<<<dim3(FFN/64, MM/128), 256, 0, stream>>>(h0b, W1T, W3T, g1);
  Ffn2Out FO; FO.p[0]=attn; FO.p[1]=p1;
  gemm_ffn2<<<dim3(EE/64, MM/128, 2), 256, 0, stream>>>(g1, W2T, FO);

  // 7. out = LN(h0 + sum of ffn partials) -> fp32 or bf16 per detected dtype
  addln_kernel<<<MM, 256, 0, stream>>>(nullptr, h0f, attn, p1, nullptr, nullptr,
                                       nullptr, nullptr, lnc[2], lnc[3],
                                       (float*)d_out, (bf16_t*)d_out, dflag);
}

// Round 15
// 321.227 us; speedup vs baseline: 1.0382x; 1.0382x over previous
//
#include <hip/hip_runtime.h>

// Longformer block, MI355X. B=2 S=2048 E=768 H=12 DH=64 W=256 G=16 FF=3072.
// R17: ffn13 counted-vmcnt dbuf = only verified schedule win (shared-A dual-B,
//      32 MFMA/step). R18/R20: T4 *transfers* falsified.
// R22: REPLICATE (not transfer) ffn13's full structure onto projections:
//      qkv fused in one block (NMAT=3: 10 loads / 48 MFMA per step, A staged
//      once for 3 outputs), kgvg fused (NMAT=2 = ffn13's exact shape).
//      128x64 tiles, dbuf 80KB/64KB -> 2 blk/CU, vmcnt(10)/vmcnt(8).
//      Rope pairs in-thread via R20-verified b-frag rows wc16 + b*32 + l15.
//      Decision: projqg <45us keep; >=50us revert R21 (terminal).

#define BB_ 2
#define SS 2048
#define EE 768
#define HH 12
#define DHH 64
#define GG 16
#define FFN 3072
#define MM (BB_*SS)   // 4096

typedef __bf16 bf16_t;
typedef __bf16 bf16x8_t __attribute__((ext_vector_type(8)));
typedef float f32x4_t __attribute__((ext_vector_type(4)));

// async global->LDS, 16B per lane; lds dest = wave-uniform base + lane*16
__device__ inline void gload16(const void* g, void* l) {
  __builtin_amdgcn_global_load_lds((const __attribute__((address_space(1))) void*)g,
                                   (__attribute__((address_space(3))) void*)l, 16, 0, 0);
}

// ---------------------------------------------------------------------------
// dtype detector (fp32 vs bf16 inputs).
// ---------------------------------------------------------------------------
__global__ __launch_bounds__(64) void detect_kernel(const unsigned int* __restrict__ w,
                                                    int* __restrict__ flag) {
  int cnt = 0;
  for (int i = threadIdx.x; i < 1024; i += 64) {
    unsigned e = (w[i] >> 7) & 0xFF;
    cnt += (e >= 100 && e <= 144) ? 1 : 0;
  }
  for (int off = 32; off; off >>= 1) cnt += __shfl_xor(cnt, off);
  if (threadIdx.x == 0) flag[0] = (cnt > 512) ? 1 : 0;   // 1 = inputs are bf16
}

// ---------------------------------------------------------------------------
// PREP: canon(x+biases+ln) | transpose x9 | flags+rope | zero accum.
// ---------------------------------------------------------------------------
struct PrepParams {
  const void* csrc[11]; bf16_t* cdst[11];
  const void* tsrc[9];  bf16_t* tdst[9];
  const int* am; const int* gm;
  float* tpos; int* flags;
  float* zbuf; int zn;
};

#define NB_CANON 3081
#define NB_T1 3456    // 6 jobs of 24x24  (EE x EE)
#define NB_T2 4608    // 2 jobs of 96x24  (EE x FFN)
#define NB_T3 2304    // 1 job  of 24x96  (FFN x EE)
#define NB_TRANS (NB_T1+NB_T2+NB_T3)

__global__ __launch_bounds__(256) void prep_kernel(PrepParams P,
                                                   const int* __restrict__ flag) {
  __shared__ bf16_t tile[32][33];
  __shared__ int wtot[4];
  int bid = blockIdx.x;
  const int t = threadIdx.x;
  const bool isb = flag[0] != 0;

  if (bid < NB_CANON) {
    constexpr int ns[11] = {3145728, 768,768,768,768,768,768, 768,768,768,768};
    int idx4 = (bid*256 + t)*4;
    int off = 0, seg = -1, loc = 0;
    #pragma unroll
    for (int i=0;i<11;i++) {
      if (seg < 0 && idx4 < off + ns[i]) { seg = i; loc = idx4 - off; }
      off += ns[i];
    }
    if (seg < 0) return;
    const void* s = P.csrc[seg];
    bf16_t* d = P.cdst[seg];
    if (isb) {
      *(uint2*)&d[loc] = *(const uint2*)((const unsigned short*)s + loc);
    } else {
      float4 v = *(const float4*)((const float*)s + loc);
      d[loc+0] = (bf16_t)v.x; d[loc+1] = (bf16_t)v.y;
      d[loc+2] = (bf16_t)v.z; d[loc+3] = (bf16_t)v.w;
    }
    return;
  }
  bid -= NB_CANON;

  if (bid < NB_TRANS) {
    int job, bx, by, R, C;
    if (bid < NB_T1)            { job = bid/576;          int r = bid%576;  bx = r%24; by = r/24; R=EE;  C=EE;  }
    else if (bid < NB_T1+NB_T2) { int l = bid-NB_T1; job = 6 + l/2304; int r = l%2304; bx = r%96; by = r/96; R=EE;  C=FFN; }
    else                        { int l = bid-NB_T1-NB_T2; job = 8;          bx = l%24; by = l/24; R=FFN; C=EE;  }
    const void* src = P.tsrc[job]; bf16_t* dst = P.tdst[job];
    int tx = t & 31, ty = t >> 5;
    int r0 = by*32, c0 = bx*32;
    #pragma unroll
    for (int i=0;i<4;i++) {
      int rr = ty + i*8;
      size_t si = (size_t)(r0+rr)*C + c0 + tx;
      tile[rr][tx] = isb ? ((const bf16_t*)src)[si] : (bf16_t)((const float*)src)[si];
    }
    __syncthreads();
    #pragma unroll
    for (int i=0;i<4;i++) {
      int cc = ty + i*8;
      dst[(size_t)(c0+cc)*R + r0 + tx] = tile[tx][cc];
    }
    return;
  }
  bid -= NB_TRANS;

  if (bid < BB_) {
    int b = bid;
    int lane = t & 63, wv = t >> 6;
    int base = b*SS + t*8;
    int mg[8]; int isg[8]; int loc = 0;
    for (int i=0;i<8;i++) {
      int a = P.am[base+i], g = P.gm[base+i];
      int merged = a*(g+1);
      mg[i] = merged;
      isg[i] = (merged==2) ? 1 : 0;
      loc += isg[i];
    }
    int x = loc;
    for (int off=1; off<64; off<<=1) {
      int y = __shfl_up(x, off);
      if (lane >= off) x += y;
    }
    if (lane==63) wtot[wv] = x;
    __syncthreads();
    int prev = 0;
    for (int w=0; w<wv; w++) prev += wtot[w];
    int run = prev + x - loc;
    for (int i=0;i<8;i++) {
      run += isg[i];
      int masked = (mg[i]==0) ? 1 : 0;
      int glob   = (mg[i]==2) ? 1 : 0;
      int rem    = (mg[i]!=1) ? 1 : 0;
      P.tpos[base+i]  = masked ? 0.f : (float)run;
      P.flags[base+i] = masked | (glob<<1) | (rem<<2);
    }
    return;
  }
  bid -= BB_;
  int i = bid*256 + t;
  if (i < P.zn) P.zbuf[i] = 0.f;
}

// ---------------------------------------------------------------------------
// Shared-A multi-B 128x64-tile K=768 GEMM core, counted-vmcnt dbuf
// (ffn13's verified schedule, generalized to NMAT B matrices).
// Per step: 4 A-loads + 2*NMAT B-loads; vmcnt(4+2*NMAT) mid-loop.
// B-fragment rows wc16 + b*32 + l15 (R20-verified rope-pair-in-thread map).
// ---------------------------------------------------------------------------
template<int NMAT>
__device__ inline void proj_core(const bf16_t* __restrict__ x,
                                 const bf16_t* __restrict__ W0,
                                 const bf16_t* __restrict__ W1,
                                 const bf16_t* __restrict__ W2,
                                 int m0, int n0,
                                 bf16_t* AsB, bf16_t* BsB,
                                 f32x4_t (&acc)[3][4][2]) {
  const int t = threadIdx.x;
  const int lane = t & 63, wv = t >> 6;
  const int l15 = lane & 15, quad = lane >> 4;
  const int wr = (wv >> 1) << 6, wc16 = (wv & 1) * 16;
  const int rsub = lane >> 3, pch = lane & 7;
  const int sch = pch ^ rsub;
  const size_t abase = (size_t)(m0 + wv*32 + rsub)*EE + sch*8;
  const size_t bbase = (size_t)(n0 + wv*16 + rsub)*EE + sch*8;
  const int sx = l15 & 7;
  const int aoff = (wv*32)*64, boff = (wv*16)*64;
  const bf16_t* Wm[3] = {W0, W1, W2};

  #define PSTAGE(buf, k0) do { \
    bf16_t* lA = AsB + (buf)*8192 + aoff; \
    _Pragma("unroll") \
    for (int j=0;j<4;j++) \
      gload16(x + abase + (size_t)(j*8)*EE + (k0), lA + j*8*64); \
    _Pragma("unroll") \
    for (int m=0;m<NMAT;m++) { \
      bf16_t* lB = BsB + (m*2+(buf))*4096 + boff; \
      _Pragma("unroll") \
      for (int j=0;j<2;j++) \
        gload16(Wm[m] + bbase + (size_t)(j*8)*EE + (k0), lB + j*8*64); \
    } } while(0)

  PSTAGE(0, 0);
  PSTAGE(1, 64);
  if constexpr (NMAT == 3) asm volatile("s_waitcnt vmcnt(10)" ::: "memory");
  else                     asm volatile("s_waitcnt vmcnt(8)"  ::: "memory");
  __builtin_amdgcn_sched_barrier(0);
  __builtin_amdgcn_s_barrier();

  for (int s = 0; s < 12; ++s) {
    const int cur = s & 1;
    const bf16_t* Ac = AsB + cur*8192;
    bf16x8_t af[2][4], bfv[3][2][2];
    #pragma unroll
    for (int c=0;c<2;c++) {
      #pragma unroll
      for (int a=0;a<4;a++)
        af[c][a] = *(const bf16x8_t*)&Ac[(wr + a*16 + l15)*64 + ((c*4+quad)^sx)*8];
      #pragma unroll
      for (int m=0;m<NMAT;m++) {
        const bf16_t* Bc = BsB + (m*2+cur)*4096;
        #pragma unroll
        for (int b=0;b<2;b++)
          bfv[m][c][b] = *(const bf16x8_t*)&Bc[(wc16 + b*32 + l15)*64 + ((c*4+quad)^sx)*8];
      }
    }
    asm volatile("s_waitcnt lgkmcnt(0)" ::: "memory");
    __builtin_amdgcn_sched_barrier(0);
    __builtin_amdgcn_s_barrier();            // all waves done reading buf[cur]
    if (s + 2 < 12) PSTAGE(cur, (s+2)*64);
    __builtin_amdgcn_s_setprio(1);
    #pragma unroll
    for (int c=0;c<2;c++)
      #pragma unroll
      for (int a=0;a<4;a++)
        #pragma unroll
        for (int m=0;m<NMAT;m++)
          #pragma unroll
          for (int b=0;b<2;b++)
            acc[m][a][b] = __builtin_amdgcn_mfma_f32_16x16x32_bf16(af[c][a], bfv[m][c][b], acc[m][a][b], 0,0,0);
    __builtin_amdgcn_s_setprio(0);
    if (s + 1 < 12) {
      if (s + 2 < 12) {
        if constexpr (NMAT == 3) asm volatile("s_waitcnt vmcnt(10)" ::: "memory");
        else                     asm volatile("s_waitcnt vmcnt(8)"  ::: "memory");
      } else {
        asm volatile("s_waitcnt vmcnt(0)" ::: "memory");
      }
      __builtin_amdgcn_sched_barrier(0);
      __builtin_amdgcn_s_barrier();
    }
  }
  #undef PSTAGE
}

// ---------------------------------------------------------------------------
// Fused projections. blocks [0,384): qkv fused (NMAT=3, rope on q,k);
// [384,768): kg+vg fused (NMAT=2); [768,864): qg tail.
// Block -> (mt = bt&31, nt = bt>>5 in [0,12)); tile 128 rows x 64 cols
// (one head). LDS: As dbuf 32KB + 3x B dbuf 48KB = 80KB -> 2 blk/CU.
// ---------------------------------------------------------------------------
struct ProjParams {
  const bf16_t* W[5];   // transposed [N][K]: Wq Wk Wv Wkg Wvg
  const bf16_t* Bi[5];
  bf16_t* O[5];
};

__global__ __launch_bounds__(256) void projqg_kernel(const bf16_t* __restrict__ x,
                                                     ProjParams P,
                                                     const float* __restrict__ tpos,
                                                     const bf16_t* __restrict__ WqgT,
                                                     const bf16_t* __restrict__ bqg,
                                                     float* __restrict__ qgb) {
  __shared__ bf16_t AsB[2*128*64];        // 32 KB
  __shared__ bf16_t BsB[3*2*64*64];       // 48 KB
  const int bid = blockIdx.x;
  const int t = threadIdx.x;
  const int lane = t & 63, wv = t >> 6;

  if (bid >= 768) {
    // ---- qg: block covers (g, hgroup, b); wave wv -> head hgroup*4+wv
    int l = bid - 768;               // [0,96)
    int g = l & 15;
    int rest = l >> 4;               // [0,6)
    int hg = rest % 3, b = rest / 3;
    float* xs = (float*)AsB;         // 768 floats = 3 KB
    for (int i=t; i<EE; i+=256) xs[i] = (float)x[((size_t)b*SS + g)*EE + i];
    __syncthreads();
    int h = hg*4 + wv, d = lane;
    float acc = 0.f;
    const bf16_t* wrow = WqgT + (size_t)(h*64+d)*EE;
    #pragma unroll 4
    for (int k=0;k<EE;k+=8) {
      bf16x8_t w8 = *(const bf16x8_t*)(wrow + k);
      #pragma unroll
      for (int i=0;i<8;i++) acc += xs[k+i] * (float)w8[i];
    }
    acc = (acc + (float)bqg[h*64+d]) * 0.125f;
    qgb[((size_t)(b*HH+h)*GG + g)*DHH + d] = acc;
    return;
  }

  const bool isqkv = (bid < 384);
  const int bt = isqkv ? bid : bid - 384;
  const int mt = bt & 31, nt = bt >> 5;    // nt in [0,12)
  const int m0 = mt * 128, n0 = nt * 64;

  f32x4_t acc[3][4][2];
  #pragma unroll
  for (int m=0;m<3;m++)
    #pragma unroll
    for (int a=0;a<4;a++)
      #pragma unroll
      for (int b=0;b<2;b++) acc[m][a][b] = (f32x4_t){0.f,0.f,0.f,0.f};

  if (isqkv) proj_core<3>(x, P.W[0], P.W[1], P.W[2], m0, n0, AsB, BsB, acc);
  else       proj_core<2>(x, P.W[3], P.W[4], P.W[4], m0, n0, AsB, BsB, acc);

  const int l15 = lane & 15, quad = lane >> 4;
  const int wr = (wv >> 1) << 6, wc16 = (wv & 1) * 16;
  const int h = nt;                      // one head per tile
  const int jf = wc16 + l15;             // rope freq index in [0,32)
  const float inv = __expf(-(float)jf * (9.210340371976184f/32.f));
  // hoisted biases: bv[z][b]
  float bv[3][2];
  const int nz = isqkv ? 3 : 2;
  #pragma unroll
  for (int z=0; z<3; z++) {
    if (z < nz) {
      const bf16_t* Bz = P.Bi[isqkv ? z : 3+z];
      bv[z][0] = (float)Bz[h*64 + wc16 + l15];
      bv[z][1] = (float)Bz[h*64 + wc16 + 32 + l15];
    }
  }
  #pragma unroll
  for (int a=0;a<4;a++) {
    #pragma unroll
    for (int r=0;r<4;r++) {
      int row = m0 + wr + a*16 + quad*4 + r;
      int bb = row >> 11, spos = row & (SS-1);
      float sn = 0.f, cs = 1.f;
      if (isqkv) {
        float tv = tpos[row];
        float ang = tv * inv;
        sn = __sinf(ang); cs = __cosf(ang);
      }
      #pragma unroll
      for (int z=0; z<3; z++) {
        if (z >= nz) continue;
        float scale = (isqkv && z==0) ? 0.125f : 1.f;
        float v0 = (acc[z][a][0][r] + bv[z][0]) * scale;
        float v1 = (acc[z][a][1][r] + bv[z][1]) * scale;
        if (isqkv && z < 2) {
          float x1 = v0, x2 = v1;
          v0 = x1*cs - x2*sn;
          v1 = x2*cs + x1*sn;
        }
        bf16_t* dst = P.O[isqkv ? z : 3+z] + ((size_t)(bb*HH + h)*SS + spos)*DHH;
        dst[wc16 + l15]      = (bf16_t)v0;
        dst[wc16 + 32 + l15] = (bf16_t)v1;
      }
    }
  }
}

// ---------------------------------------------------------------------------
// Fused FFN1+FFN3: g1 = silu(h0@W1) * (h0@W3). 128x64 tile, dual accumulators.
// R17 counted-vmcnt double-buffer (verified win).
// ---------------------------------------------------------------------------
__global__ __launch_bounds__(256) void gemm_ffn13(const bf16_t* __restrict__ A,
                                                  const bf16_t* __restrict__ B1T,
                                                  const bf16_t* __restrict__ B3T,
                                                  bf16_t* __restrict__ g1) {
  const int n0 = blockIdx.x*64, m0 = blockIdx.y*128;
  __shared__ bf16_t As[2][128*64];
  __shared__ bf16_t Bs1[2][64*64];
  __shared__ bf16_t Bs3[2][64*64];
  const int t = threadIdx.x;
  const int lane = t & 63, wv = t >> 6;
  const int l15 = lane & 15, quad = lane >> 4;
  const int wr = (wv >> 1) << 6, wc = (wv & 1) << 5;   // 64 rows x 32 cols / wave
  const int rsub = lane >> 3, pch = lane & 7;
  const int sch = pch ^ rsub;                          // swizzled source chunk
  const size_t abase = (size_t)(m0 + wv*32 + rsub)*EE + sch*8;
  const size_t bbase = (size_t)(n0 + wv*16 + rsub)*EE + sch*8;
  const int sx = l15 & 7;
  const int aoff = (wv*32)*64, boff = (wv*16)*64;

  f32x4_t a1[4][2], a3[4][2];
  #pragma unroll
  for (int a=0;a<4;a++)
    #pragma unroll
    for (int b=0;b<2;b++) { a1[a][b] = (f32x4_t){0.f,0.f,0.f,0.f};
                            a3[a][b] = (f32x4_t){0.f,0.f,0.f,0.f}; }

  #define FFN13_STAGE(buf, k0) do { \
    bf16_t* lA  = &As[buf][aoff]; \
    bf16_t* lB1 = &Bs1[buf][boff]; \
    bf16_t* lB3 = &Bs3[buf][boff]; \
    _Pragma("unroll") \
    for (int j=0;j<4;j++) \
      gload16(A + abase + (size_t)(j*8)*EE + (k0), lA + j*8*64); \
    _Pragma("unroll") \
    for (int j=0;j<2;j++) { \
      gload16(B1T + bbase + (size_t)(j*8)*EE + (k0), lB1 + j*8*64); \
      gload16(B3T + bbase + (size_t)(j*8)*EE + (k0), lB3 + j*8*64); \
    } } while(0)

  FFN13_STAGE(0, 0);
  FFN13_STAGE(1, 64);
  asm volatile("s_waitcnt vmcnt(8)" ::: "memory");
  __builtin_amdgcn_sched_barrier(0);
  __builtin_amdgcn_s_barrier();

  for (int s = 0; s < 12; ++s) {
    const int cur = s & 1;
    const bf16_t* Ac = As[cur];
    const bf16_t* C1 = Bs1[cur];
    const bf16_t* C3 = Bs3[cur];
    bf16x8_t af[2][4], b1f[2][2], b3f[2][2];
    #pragma unroll
    for (int c=0;c<2;c++) {
      #pragma unroll
      for (int a=0;a<4;a++)
        af[c][a] = *(const bf16x8_t*)&Ac[(wr + a*16 + l15)*64 + ((c*4+quad)^sx)*8];
      #pragma unroll
      for (int b=0;b<2;b++) {
        b1f[c][b] = *(const bf16x8_t*)&C1[(wc + b*16 + l15)*64 + ((c*4+quad)^sx)*8];
        b3f[c][b] = *(const bf16x8_t*)&C3[(wc + b*16 + l15)*64 + ((c*4+quad)^sx)*8];
      }
    }
    asm volatile("s_waitcnt lgkmcnt(0)" ::: "memory");
    __builtin_amdgcn_sched_barrier(0);
    __builtin_amdgcn_s_barrier();            // all waves done reading buf[cur]
    if (s + 2 < 12) FFN13_STAGE(cur, (s+2)*64);
    __builtin_amdgcn_s_setprio(1);
    #pragma unroll
    for (int c=0;c<2;c++)
      #pragma unroll
      for (int a=0;a<4;a++)
        #pragma unroll
        for (int b=0;b<2;b++) {
          a1[a][b] = __builtin_amdgcn_mfma_f32_16x16x32_bf16(af[c][a], b1f[c][b], a1[a][b], 0,0,0);
          a3[a][b] = __builtin_amdgcn_mfma_f32_16x16x32_bf16(af[c][a], b3f[c][b], a3[a][b], 0,0,0);
        }
    __builtin_amdgcn_s_setprio(0);
    if (s + 1 < 12) {
      if (s + 2 < 12) {
        asm volatile("s_waitcnt vmcnt(8)" ::: "memory");
      } else {
        asm volatile("s_waitcnt vmcnt(0)" ::: "memory");
      }
      __builtin_amdgcn_sched_barrier(0);
      __builtin_amdgcn_s_barrier();
    }
  }
  #undef FFN13_STAGE

  #pragma unroll
  for (int a=0;a<4;a++)
    #pragma unroll
    for (int r=0;r<4;r++) {
      int row = m0 + wr + a*16 + quad*4 + r;
      #pragma unroll
      for (int b=0;b<2;b++) {
        float tv = a1[a][b][r];
        float sil = tv / (1.f + __expf(-tv));
        g1[(size_t)row*FFN + n0 + wc + b*16 + l15] = (bf16_t)(sil * a3[a][b][r]);
      }
    }
}

// ---------------------------------------------------------------------------
// FFN down, 128x64 tile (single-buf), split-K=2 (R16 form).
// ---------------------------------------------------------------------------
struct Ffn2Out { float* p[2]; };

__global__ __launch_bounds__(256) void gemm_ffn2(const bf16_t* __restrict__ A,
                                                 const bf16_t* __restrict__ BT,
                                                 Ffn2Out O) {
  const int n0 = blockIdx.x*64, m0 = blockIdx.y*128;
  const int kz = blockIdx.z;
  __shared__ bf16_t As[128*64];
  __shared__ bf16_t Bs[64*64];
  const int t = threadIdx.x;
  const int lane = t & 63, wv = t >> 6;
  const int l15 = lane & 15, quad = lane >> 4;
  const int wr = (wv >> 1) << 6, wc = (wv & 1) << 5;   // 64 rows x 32 cols / wave
  const int rsub = lane >> 3, pch = lane & 7;
  const int sch = pch ^ rsub;
  const size_t abase = (size_t)(m0 + wv*32 + rsub)*FFN + sch*8;
  const size_t bbase = (size_t)(n0 + wv*16 + rsub)*FFN + sch*8;
  const int sx = l15 & 7;
  bf16_t* lA = As + (wv*32)*64;
  bf16_t* lB = Bs + (wv*16)*64;
  f32x4_t acc[4][2];
  #pragma unroll
  for (int a=0;a<4;a++)
    #pragma unroll
    for (int b=0;b<2;b++) acc[a][b] = (f32x4_t){0.f,0.f,0.f,0.f};
  const int kbeg = kz*1536, kend = kbeg + 1536;
  for (int k0 = kbeg; k0 < kend; k0 += 64) {
    __syncthreads();
    #pragma unroll
    for (int j=0;j<4;j++)
      gload16(A + abase + (size_t)(j*8)*FFN + k0, lA + j*8*64);
    #pragma unroll
    for (int j=0;j<2;j++)
      gload16(BT + bbase + (size_t)(j*8)*FFN + k0, lB + j*8*64);
    __syncthreads();
    #pragma unroll
    for (int c=0;c<2;c++) {
      bf16x8_t af[4], bfv[2];
      #pragma unroll
      for (int a=0;a<4;a++)
        af[a] = *(const bf16x8_t*)&As[(wr + a*16 + l15)*64 + ((c*4+quad)^sx)*8];
      #pragma unroll
      for (int b=0;b<2;b++)
        bfv[b] = *(const bf16x8_t*)&Bs[(wc + b*16 + l15)*64 + ((c*4+quad)^sx)*8];
      #pragma unroll
      for (int a=0;a<4;a++)
        #pragma unroll
        for (int b=0;b<2;b++)
          acc[a][b] = __builtin_amdgcn_mfma_f32_16x16x32_bf16(af[a], bfv[b], acc[a][b], 0,0,0);
    }
  }
  float* C = O.p[kz];
  #pragma unroll
  for (int a=0;a<4;a++)
    #pragma unroll
    for (int r=0;r<4;r++) {
      int row = m0 + wr + a*16 + quad*4 + r;
      #pragma unroll
      for (int b=0;b<2;b++)
        C[(size_t)row*EE + n0 + wc + b*16 + l15] = acc[a][b][r];
    }
}

// ---------------------------------------------------------------------------
// Band (sliding-window) attention, MFMA. QBLK=64, standalone (48 VGPR shape).
// ---------------------------------------------------------------------------
__global__ __launch_bounds__(256) void band_kernel(const bf16_t* __restrict__ qb,
                                                   const bf16_t* __restrict__ kb,
                                                   const bf16_t* __restrict__ vb,
                                                   const int* __restrict__ flags,
                                                   float* __restrict__ attn) {
  const int flat = blockIdx.x;
  const int nb = (flat & 7) * 96 + (flat >> 3);
  const int px = nb & 31;
  const int hb = nb >> 5;              // 0..23
  const int h = hb % HH, b = hb / HH;
  const int p0 = px * 64;

  const int t = threadIdx.x;
  const int wv = t>>6, lane = t&63;
  const int l15 = lane & 15, quad = lane >> 4;
  const size_t bh = (size_t)(b*HH+h);
  const bf16_t* kbh = kb + bh*SS*DHH;
  const bf16_t* vbh = vb + bh*SS*DHH;
  const int* fl = flags + b*SS;
  const int q0 = p0 + wv*16;

  __shared__ bf16_t Ks[2][64*DHH];      // [buf][key][dh], XOR chunk-swizzled
  __shared__ bf16_t Vt[2][64*72];       // [buf][dh][key]
  __shared__ bf16_t Pw[4][16*72];       // per-wave P [q][key]

  const bf16_t* qrow = qb + (bh*SS + q0 + l15)*DHH;
  bf16x8_t qa0 = *(const bf16x8_t*)(qrow + quad*8);
  bf16x8_t qa1 = *(const bf16x8_t*)(qrow + 32 + quad*8);

  const int srsub = lane >> 3, spch = lane & 7;
  const int vkp  = (t & 31) * 2;
  const int vdh0 = (t >> 5) * 8;

  // ---- prologue: stage unit 0 into buf 0
  {
    const int kb0 = p0 - 256;
    #pragma unroll
    for (int j=0;j<2;j++) {
      int row = wv*16 + j*8 + srsub;
      int kc = min(max(kb0 + row, 0), SS-1);
      gload16(kbh + (size_t)kc*DHH + (spch ^ srsub)*8, &Ks[0][(wv*16 + j*8)*DHH]);
    }
    int kc1 = min(max(kb0 + vkp,   0), SS-1);
    int kc2 = min(max(kb0 + vkp+1, 0), SS-1);
    bf16x8_t v1 = *(const bf16x8_t*)(vbh + (size_t)kc1*DHH + vdh0);
    bf16x8_t v2 = *(const bf16x8_t*)(vbh + (size_t)kc2*DHH + vdh0);
    #pragma unroll
    for (int i=0;i<8;i++) {
      union { unsigned u; bf16_t hh[2]; } pk;
      pk.hh[0] = v1[i]; pk.hh[1] = v2[i];
      *(unsigned*)&Vt[0][(vdh0+i)*72 + vkp] = pk.u;
    }
  }
  __syncthreads();

  f32x4_t o[4];
  #pragma unroll
  for (int i=0;i<4;i++) o[i] = (f32x4_t){0.f,0.f,0.f,0.f};
  float lsum[4] = {0.f,0.f,0.f,0.f};
  bf16_t* P = Pw[wv];

  for (int unit=0; unit<10; unit++) {
    const int cur = unit & 1, nxt = cur ^ 1;
    const int kb0 = (unit<9) ? (p0 - 256 + unit*64) : 0;
    const bool pre = (unit < 9);
    bf16x8_t pv1, pv2;
    if (pre) {
      const int kbn = (unit < 8) ? (kb0 + 64) : 0;
      #pragma unroll
      for (int j=0;j<2;j++) {
        int row = wv*16 + j*8 + srsub;
        int kc = min(max(kbn + row, 0), SS-1);
        gload16(kbh + (size_t)kc*DHH + (spch ^ srsub)*8, &Ks[nxt][(wv*16 + j*8)*DHH]);
      }
      int kc1 = min(max(kbn + vkp,   0), SS-1);
      int kc2 = min(max(kbn + vkp+1, 0), SS-1);
      pv1 = *(const bf16x8_t*)(vbh + (size_t)kc1*DHH + vdh0);
      pv2 = *(const bf16x8_t*)(vbh + (size_t)kc2*DHH + vdh0);
    }
    // ---- QK^T + exp from Ks[cur]
    const bf16_t* Kc = Ks[cur];
    const int nsub = (unit<9) ? 4 : 1;
    for (int sub=0; sub<4; sub++) {
      if (sub < nsub) {
        int krow = sub*16 + l15;
        int kpos = kb0 + krow;
        bf16x8_t kf0 = *(const bf16x8_t*)&Kc[krow*DHH + (((quad  ) ^ (krow&7))<<3)];
        bf16x8_t kf1 = *(const bf16x8_t*)&Kc[krow*DHH + (((quad+4) ^ (krow&7))<<3)];
        f32x4_t s = (f32x4_t){0.f,0.f,0.f,0.f};
        s = __builtin_amdgcn_mfma_f32_16x16x32_bf16(qa0, kf0, s, 0,0,0);
        s = __builtin_amdgcn_mfma_f32_16x16x32_bf16(qa1, kf1, s, 0,0,0);
        int kc = min(max(kpos,0),SS-1);
        bool drop = false;
        if (unit<9) drop = (kpos<0) || (kpos>=SS) || (((fl[kc]>>2)&1)!=0);
        #pragma unroll
        for (int r=0;r<4;r++) {
          float e;
          if (unit==9) {
            e = __expf(s[r]);
          } else {
            int dj = kpos - (q0 + quad*4 + r);
            bool valid = (dj>=-256) && (dj<=256) && (!drop);
            e = valid ? __expf(s[r]) : 0.f;
          }
          lsum[r] += e;
          P[(quad*4+r)*72 + sub*16 + l15] = (bf16_t)e;
        }
      } else {
        #pragma unroll
        for (int r=0;r<4;r++) P[(quad*4+r)*72 + sub*16 + l15] = (bf16_t)0.f;
      }
    }
    // ---- P @ V from Vt[cur]
    __builtin_amdgcn_s_setprio(1);
    #pragma unroll
    for (int chunk=0; chunk<2; chunk++) {
      bf16x8_t pf = *(const bf16x8_t*)&P[l15*72 + chunk*32 + quad*8];
      #pragma unroll
      for (int nt=0; nt<4; nt++) {
        bf16x8_t vf = *(const bf16x8_t*)&Vt[cur][(nt*16+l15)*72 + chunk*32 + quad*8];
        o[nt] = __builtin_amdgcn_mfma_f32_16x16x32_bf16(pf, vf, o[nt], 0,0,0);
      }
    }
    __builtin_amdgcn_s_setprio(0);
    // ---- late transpose-write of prefetched V into the free buffer
    if (pre) {
      #pragma unroll
      for (int i=0;i<8;i++) {
        union { unsigned u; bf16_t hh[2]; } pk;
        pk.hh[0] = pv1[i]; pk.hh[1] = pv2[i];
        *(unsigned*)&Vt[nxt][(vdh0+i)*72 + vkp] = pk.u;
      }
      __syncthreads();   // one barrier per unit; implicit vmcnt(0) drains gload_lds
    }
  }
  #pragma unroll
  for (int r=0;r<4;r++) {
    float s = lsum[r];
    s += __shfl_xor(s,1); s += __shfl_xor(s,2);
    s += __shfl_xor(s,4); s += __shfl_xor(s,8);
    lsum[r] = s;
  }
  #pragma unroll
  for (int r=0;r<4;r++) {
    int q = q0 + quad*4 + r;
    int masked = fl[q] & 1;
    float inv = masked ? 0.f : 1.f/lsum[r];
    float* dst = attn + ((size_t)(b*SS+q))*EE + h*64 + l15;
    #pragma unroll
    for (int nt=0; nt<4; nt++) dst[nt*16] = o[nt][r]*inv;
  }
}

// ---------------------------------------------------------------------------
// Global attention, key-split partials (finalize folded into addln).
// ---------------------------------------------------------------------------
__global__ __launch_bounds__(256) void gattn_part(const float* __restrict__ qgb,
                                                  const bf16_t* __restrict__ kgb,
                                                  const bf16_t* __restrict__ vgb,
                                                  const int* __restrict__ flags,
                                                  float* __restrict__ go,
                                                  float* __restrict__ gl) {
  const int kbase = blockIdx.x*128;
  const int h = blockIdx.y, b = blockIdx.z;
  const int t = threadIdx.x;
  __shared__ float gqs[16*68];
  __shared__ float Ks[64*68];
  __shared__ float Vs[64*68];
  __shared__ float es[16*64];
  const size_t bh = (size_t)(b*HH+h);
  #pragma unroll
  for (int j=0;j<4;j++) {
    int idx = t + j*256;
    int g = idx>>6, d = idx&63;
    gqs[g*68+d] = qgb[(bh*GG + g)*DHH + d];
  }
  float accv[4] = {0.f,0.f,0.f,0.f};
  float lpart = 0.f;
  const int gs = t>>4, kslot = t&15;
  const int dp = t&63, grp = t>>6;
  const bf16_t* kb_ = kgb + bh*SS*DHH;
  const bf16_t* vb_ = vgb + bh*SS*DHH;
  const int* fl = flags + b*SS;
  for (int tile=0; tile<2; tile++) {
    int k0 = kbase + tile*64;
    __syncthreads();
    {
      int row = t>>2, seg = t&3;
      const bf16_t* sk = kb_ + (size_t)(k0+row)*DHH + seg*16;
      const bf16_t* sv = vb_ + (size_t)(k0+row)*DHH + seg*16;
      bf16x8_t k1 = *(const bf16x8_t*)sk;
      bf16x8_t k2 = *(const bf16x8_t*)(sk+8);
      bf16x8_t v1 = *(const bf16x8_t*)sv;
      bf16x8_t v2 = *(const bf16x8_t*)(sv+8);
      #pragma unroll
      for (int i=0;i<8;i++) {
        Ks[row*68 + seg*16 + i]     = (float)k1[i];
        Ks[row*68 + seg*16 + 8 + i] = (float)k2[i];
        Vs[row*68 + seg*16 + i]     = (float)v1[i];
        Vs[row*68 + seg*16 + 8 + i] = (float)v2[i];
      }
    }
    __syncthreads();
    #pragma unroll
    for (int j=0;j<4;j++) {
      int key = kslot + 16*j;
      const float* gq = &gqs[gs*68];
      const float* kr = &Ks[key*68];
      float s = 0.f;
      #pragma unroll
      for (int d4=0; d4<64; d4+=4) {
        float4 a = *(const float4*)(gq + d4);
        float4 kk = *(const float4*)(kr + d4);
        s += a.x*kk.x + a.y*kk.y + a.z*kk.z + a.w*kk.w;
      }
      int msk = fl[k0+key] & 1;
      float e = msk ? 0.f : __expf(s);
      es[gs*64+key] = e;
      lpart += e;
    }
    __syncthreads();
    #pragma unroll 8
    for (int key=0; key<64; key++) {
      float vv = Vs[key*68+dp];
      #pragma unroll
      for (int g=0; g<4; g++)
        accv[g] += es[(grp*4+g)*64+key]*vv;
    }
  }
  __syncthreads();
  es[gs*64 + kslot] = lpart;
  __syncthreads();
  if (t < 16) {
    float s = 0.f;
    for (int j=0;j<16;j++) s += es[t*64+j];
    atomicAdd(&gl[bh*16 + t], s);
  }
  #pragma unroll
  for (int g=0; g<4; g++)
    atomicAdd(&go[(bh*16 + grp*4+g)*64 + dp], accv[g]);
}

// ---------------------------------------------------------------------------
// Residual add + LayerNorm. B-side = sum of up to 4 fp32 partials (each
// individually optional). If gof!=nullptr, rows with (r mod S) < G take the
// attention value from go/gl (global-attention overwrite) instead of B0.
// ---------------------------------------------------------------------------
__global__ __launch_bounds__(256) void addln_kernel(const bf16_t* __restrict__ Abf,
                                                    const float* __restrict__ Af,
                                                    const float* __restrict__ B0,
                                                    const float* __restrict__ B1,
                                                    const float* __restrict__ B2,
                                                    const float* __restrict__ B3,
                                                    const float* __restrict__ gof,
                                                    const float* __restrict__ glf,
                                                    const bf16_t* __restrict__ gw,
                                                    const bf16_t* __restrict__ bw,
                                                    float* __restrict__ outf,
                                                    bf16_t* __restrict__ outb,
                                                    const int* __restrict__ flagp) {
  int r = blockIdx.x, t = threadIdx.x;
  int lane = t&63, wv = t>>6;
  int spos = r & (SS-1), bb = r >> 11;
  bool isglob = (gof != nullptr) && (spos < GG);
  float v[3]; float sum=0.f, ss=0.f;
  #pragma unroll
  for (int j=0;j<3;j++) {
    int idx = t + j*256;
    size_t gi = (size_t)r*EE+idx;
    float a = Abf ? (float)Abf[gi] : Af[gi];
    float bv;
    if (isglob) {
      int hh = idx >> 6, dp = idx & 63;
      int slot = (bb*HH + hh)*GG + spos;
      bv = gof[(size_t)slot*DHH + dp] / glf[slot];
    } else {
      bv = B0[gi];
    }
    float val = a + bv;
    if (B1) val += B1[gi];
    if (B2) val += B2[gi];
    if (B3) val += B3[gi];
    v[j] = val; sum += val; ss += val*val;
  }
  #pragma unroll
  for (int off=32; off>=1; off>>=1) {
    sum += __shfl_xor(sum, off);
    ss  += __shfl_xor(ss, off);
  }
  __shared__ float s1[4], s2[4];
  if (lane==0) { s1[wv]=sum; s2[wv]=ss; }
  __syncthreads();
  sum = s1[0]+s1[1]+s1[2]+s1[3];
  ss  = s2[0]+s2[1]+s2[2]+s2[3];
  float mean = sum * (1.f/(float)EE);
  float var  = ss * (1.f/(float)EE) - mean*mean;
  float rstd = rsqrtf(var + 1e-5f);
  bool wantb, wantf;
  if (flagp) { bool isb = (*flagp)!=0; wantb = isb; wantf = !isb; }
  else { wantb = (outb!=nullptr); wantf = (outf!=nullptr); }
  #pragma unroll
  for (int j=0;j<3;j++) {
    int idx = t + j*256;
    float o = (v[j]-mean)*rstd*(float)gw[idx] + (float)bw[idx];
    if (wantf) outf[(size_t)r*EE+idx] = o;
    if (wantb) outb[(size_t)r*EE+idx] = (bf16_t)o;
  }
}

// ---------------------------------------------------------------------------
extern "C" void kernel_launch(void* const* d_in, const int* in_sizes, int n_in,
                              void* d_out, int out_size, void* d_ws, size_t ws_size,
                              hipStream_t stream) {
  const void* x_r    = d_in[0];
  const int* am      = (const int*)d_in[1];
  const int* gm      = (const int*)d_in[2];
  (void)in_sizes; (void)n_in; (void)out_size; (void)ws_size;

  char* ws = (char*)d_ws;
  size_t off = 0;
  auto alloc = [&](size_t bytes) -> void* {
    void* p = ws + off;
    off += (bytes + 255) & ~(size_t)255;
    return p;
  };
  // canonical bf16 tensors (weights transposed to [N][K])
  bf16_t* xc    = (bf16_t*)alloc((size_t)MM*EE*2);
  bf16_t* WT[6]; bf16_t* bc[6];
  for (int i=0;i<6;i++) { WT[i] = (bf16_t*)alloc((size_t)EE*EE*2); bc[i] = (bf16_t*)alloc(EE*2); }
  bf16_t* lnc[4];
  for (int i=0;i<4;i++) lnc[i] = (bf16_t*)alloc(EE*2);
  bf16_t* W1T = (bf16_t*)alloc((size_t)EE*FFN*2);
  bf16_t* W3T = (bf16_t*)alloc((size_t)EE*FFN*2);
  bf16_t* W2T = (bf16_t*)alloc((size_t)FFN*EE*2);
  // intermediates
  const size_t NBHSD = (size_t)BB_*HH*SS*DHH;
  bf16_t* qb    = (bf16_t*)alloc(NBHSD*2);
  bf16_t* kb    = (bf16_t*)alloc(NBHSD*2);
  bf16_t* vb    = (bf16_t*)alloc(NBHSD*2);
  bf16_t* kgb   = (bf16_t*)alloc(NBHSD*2);
  bf16_t* vgb   = (bf16_t*)alloc(NBHSD*2);
  float* qgb   = (float*)alloc((size_t)BB_*HH*GG*DHH*4);
  float* attn  = (float*)alloc((size_t)MM*EE*4);    // reused as ffn2 partial 0
  float* h0f   = (float*)alloc((size_t)MM*EE*4);
  bf16_t* h0b  = (bf16_t*)alloc((size_t)MM*EE*2);
  bf16_t* g1   = (bf16_t*)alloc((size_t)MM*FFN*2);
  float* go    = (float*)alloc((size_t)BB_*HH*GG*DHH*4);  // 24576 f32
  float* gl    = (float*)alloc((size_t)BB_*HH*GG*4);      // 384 f32 (contiguous)
  float* tposb = (float*)alloc((size_t)BB_*SS*4);
  int*   flagb = (int*)alloc((size_t)BB_*SS*4);
  int*   dflag = (int*)alloc(256);
  // ffn2 partial 1 aliases qb+kb (12.6MB fp32, dead after attention)
  float* p1 = (float*)qb;

  // 0. dtype detect on Wq
  detect_kernel<<<1, 64, 0, stream>>>((const unsigned int*)d_in[3], dflag);

  // 1. prep: canon + 9 transposes + flags/rope + zero accumulators (ONE launch)
  PrepParams PP;
  const void* csrc[11] = { x_r, d_in[4], d_in[6], d_in[8], d_in[10], d_in[12], d_in[14],
                           d_in[15], d_in[16], d_in[17], d_in[18] };
  bf16_t* cdst[11] = { xc, bc[0], bc[1], bc[2], bc[3], bc[4], bc[5],
                       lnc[0], lnc[1], lnc[2], lnc[3] };
  for (int i=0;i<11;i++) { PP.csrc[i]=csrc[i]; PP.cdst[i]=cdst[i]; }
  const int wi[6] = {3,5,7,9,11,13};                 // Wq Wk Wv Wqg Wkg Wvg
  for (int i=0;i<6;i++) { PP.tsrc[i]=d_in[wi[i]]; PP.tdst[i]=WT[i]; }
  PP.tsrc[6]=d_in[19]; PP.tdst[6]=W1T;
  PP.tsrc[7]=d_in[20]; PP.tdst[7]=W3T;
  PP.tsrc[8]=d_in[21]; PP.tdst[8]=W2T;
  PP.am = am; PP.gm = gm; PP.tpos = tposb; PP.flags = flagb;
  PP.zbuf = go; PP.zn = 24960;                       // go+gl contiguous
  prep_kernel<<<NB_CANON + NB_TRANS + BB_ + 98, 256, 0, stream>>>(PP, dflag);

  // 2. fused projections: qkv blocks (384) + kgvg blocks (384) + qg (96)
  ProjParams P;
  P.W[0]=WT[0]; P.Bi[0]=bc[0]; P.O[0]=qb;
  P.W[1]=WT[1]; P.Bi[1]=bc[1]; P.O[1]=kb;
  P.W[2]=WT[2]; P.Bi[2]=bc[2]; P.O[2]=vb;
  P.W[3]=WT[4]; P.Bi[3]=bc[4]; P.O[3]=kgb;   // Wkg
  P.W[4]=WT[5]; P.Bi[4]=bc[5]; P.O[4]=vgb;   // Wvg
  projqg_kernel<<<dim3(864), 256, 0, stream>>>(xc, P, tposb, WT[3], bc[3], qgb);

  // 3. band attention (standalone, 768 blocks, XCD-swizzled)
  band_kernel<<<dim3(768), 256, 0, stream>>>(qb, kb, vb, flagb, attn);

  // 4. global-attention rows (key-split partials; finalize folded into addln)
  gattn_part<<<dim3(SS/128, HH, BB_), 256, 0, stream>>>(qgb, kgb, vgb, flagb, go, gl);

  // 5. h0 = LN(x + attn)   (rows < G take go/gl)
  addln_kernel<<<MM, 256, 0, stream>>>(xc, nullptr, attn, nullptr, nullptr, nullptr,
                                       go, gl, lnc[0], lnc[1], h0f, h0b, nullptr);

  // 6. FFN: fused ffn13 (dbuf, verified) -> g1, then 128x64 splitK2 down-proj
  gemm_ffn13<<<dim3(FFN/64, MM/128), 256, 0, stream>>>(h0b, W1T, W3T, g1);
  Ffn2Out FO; FO.p[0]=attn; FO.p[1]=p1;
  gemm_ffn2<<<dim3(EE/64, MM/128, 2), 256, 0, stream>>>(g1, W2T, FO);

  // 7. out = LN(h0 + sum of ffn partials) -> fp32 or bf16 per detected dtype
  addln_kernel<<<MM, 256, 0, stream>>>(nullptr, h0f, attn, p1, nullptr, nullptr,
                                       nullptr, nullptr, lnc[2], lnc[3],
                                       (float*)d_out, (bf16_t*)d_out, dflag);
}